// Round 18
// baseline (396.787 us; speedup 1.0000x reference)
//
#include <hip/hip_runtime.h>
#include <math.h>

// EmergentResonator — R19: 12 waves x NTILE=2, register budget pinned.
// R18 (best 314us): VALU 40%, MFMA 15%, Occ 23% — nothing saturated, ~45% of
// the step is latency at 2 waves/SIMD. R15 (the prior 12-wave test, -8%) had
// two confounds: it ran pre-R16 (VALU 54%, near-saturated -> waves can't
// help) and launch_bounds(768,1) squeezed VGPR to 76 (ILP loss). R19 retests
// the wave lever on the slimmed kernel with the budget pinned:
//  - 768 thr = 12 waves x NTILE=2 (24 n-tiles), neuron 12->8 outputs/thread,
//    GEMM 24 MFMAs/wave, 3 waves/SIMD structural (LDS ~112KB, 1 blk/CU).
//  - __launch_bounds__(768) + amdgpu_waves_per_eu(3,3): budget 170 regs ->
//    allocator keeps ~110 (sentinel: VGPR ~76 = hint failed, revert).
//  - Wl dropped (R17: input weights from L2 are fully overlapped); rbh[6][2]
//    kt0-5 in regs; Bc kt6-9 in LDS (96KB); kt10-11 streamed.
//  - LN finish = R15's validated 12-wave 8+4 pre-add. FP per-row identical.
// PRE-COMMIT: regression -> R18 is the plateau; close with it.
// Sentinels: absmax == 0.015625; WRITE ~160KB; VGPR 100-115; Occ ~34.

#define NET    360
#define NPAD   384
#define K8N    48          // NPAD/8 k8-groups for W_rec
#define RPB    16
#define NBLK   256
#define NTHR   768         // 12 waves; wave w owns n-tiles 2w, 2w+1
#define NW     12
#define NTILE  2

typedef _Float16 f16x8 __attribute__((ext_vector_type(8)));
typedef float    f32x4 __attribute__((ext_vector_type(4)));

#define WREC_E (K8N * NPAD * 8)    // 147456 f16 per term
#define WIN_E  (4 * NPAD * 8)      // 12288 f16 per term (K pad 32)

// Split fp32 weights into f16 hi/lo in MFMA B-fragment layout:
// idx = (k8*NPAD + n)*8 + (k&7), B[k][n] = W[n*K + k], zero-padded.
__global__ void prep_kernel(const float* __restrict__ W_rec,
                            const float* __restrict__ W_in,
                            const float* __restrict__ W_gate,
                            _Float16* __restrict__ Bh, _Float16* __restrict__ Bl,
                            _Float16* __restrict__ Wio)
{
    int idx = blockIdx.x * 256 + threadIdx.x;
    if (idx < WREC_E) {
        int k8 = idx / (NPAD * 8), rem = idx % (NPAD * 8);
        int n = rem >> 3, j = rem & 7, k = k8 * 8 + j;
        float v = (k < NET && n < NET) ? W_rec[n * NET + k] : 0.f;
        _Float16 h = (_Float16)v;
        Bh[idx] = h; Bl[idx] = (_Float16)(v - (float)h);
    } else if (idx < WREC_E + 2 * WIN_E) {
        // Wio layout: [0]=Wih, [1]=Wil, [2]=Wgh, [3]=Wgl, each WIN_E f16.
        int e = idx - WREC_E;                 // 0 .. 2*WIN_E-1
        int which = e / WIN_E;                // 0 = W_in, 1 = W_gate
        int f = e % WIN_E;
        int k8 = f / (NPAD * 8), rem = f % (NPAD * 8);
        int n = rem >> 3, j = rem & 7, k = k8 * 8 + j;
        const float* W = which ? W_gate : W_in;
        float v = (k < 28 && n < NET) ? W[n * 28 + k] : 0.f;
        _Float16 h = (_Float16)v;
        Wio[(2 * which) * WIN_E + f]     = h;
        Wio[(2 * which + 1) * WIN_E + f] = (_Float16)(v - (float)h);
    }
}

// Hardware-rcp sigmoid: v_rcp_f32 is ~1ulp; error << the accepted 2^-11 floor.
__device__ __forceinline__ float sigm(float v) {
    return __builtin_amdgcn_rcpf(1.f + __expf(-v));
}

__global__ __launch_bounds__(NTHR)
__attribute__((amdgpu_waves_per_eu(3, 3)))
void resonator_kernel(const float* __restrict__ x,
                      const int*   __restrict__ rsteps_p,
                      const float* __restrict__ b_in,
                      const float* __restrict__ b_gate,
                      const float* __restrict__ ln_g,
                      const float* __restrict__ ln_b,
                      const float* __restrict__ thr_p,
                      const float* __restrict__ intr_p,
                      const float* __restrict__ steep_p,
                      const float* __restrict__ reset_p,
                      const float* __restrict__ W_cls,
                      const float* __restrict__ b_cls,
                      const _Float16* __restrict__ Bh_g,
                      const _Float16* __restrict__ Bl_g,
                      const _Float16* __restrict__ Wio_g,
                      float* __restrict__ out)
{
    // Spikes in A-fragment layout, f16 (h only): idx = (k8*16 + m)*8 + (k&7)
    __shared__ __align__(16) _Float16 Ah[K8N * RPB * 8];       // 12 KB
    __shared__ __align__(16) _Float16 xbuf[2][4 * RPB * 8];    // 2 KB [parity]
    __shared__ __align__(16) _Float16 Bc[NW * 8 * 64 * 8];     // 96 KB: bh kt6-9
    __shared__ float red[NW][33];                              // LN partials

    const int tid  = threadIdx.x;
    const int w    = tid >> 6;
    const int lane = tid & 63;
    const int quad = lane >> 4;
    const int l15  = lane & 15;
    const int row0 = blockIdx.x * RPB;

    // Per-column params for this thread's NTILE n-values (n = (w*2+i)*16 + l15)
    float gam[NTILE], bet[NTILE], thrv[NTILE], intv[NTILE], asp[NTILE], rscv[NTILE],
          binv[NTILE], bgtv[NTILE];
#pragma unroll
    for (int i = 0; i < NTILE; ++i) {
        int n_i = (w * NTILE + i) * 16 + l15;
        bool a = n_i < NET;
        gam[i]  = a ? ln_g[n_i]   : 0.f;
        bet[i]  = a ? ln_b[n_i]   : 0.f;
        thrv[i] = a ? thr_p[n_i]  : 0.f;
        intv[i] = a ? intr_p[n_i] : 0.f;
        asp[i]  = a ? fabsf(steep_p[n_i]) : 0.f;
        rscv[i] = a ? reset_p[n_i] : 0.f;
        binv[i] = a ? b_in[n_i]   : 0.f;
        bgtv[i] = a ? b_gate[n_i] : 0.f;
    }

    float pot[NTILE][4];
#pragma unroll
    for (int i = 0; i < NTILE; ++i)
#pragma unroll
        for (int r = 0; r < 4; ++r) pot[i][r] = 0.f;

    // Zero-init spike + x LDS (x pad cols stay 0 forever).
    for (int e = tid; e < K8N * RPB * 8; e += NTHR) Ah[e] = (_Float16)0.f;
    for (int e = tid; e < 2 * 4 * RPB * 8; e += NTHR) ((_Float16*)xbuf)[e] = (_Float16)0.f;
    __syncthreads();   // zero-init visible before cross-wave scattered staging

    const f16x8* Bph = (const f16x8*)Bh_g;
    const f16x8* Aph = (const f16x8*)Ah;
    const f16x8* Wp  = (const f16x8*)Wio_g;     // input weights: global (L2-hot)
    f16x8* Bcv = (f16x8*)Bc;
    const int bb = quad * NPAD + w * (NTILE * 16) + l15;  // B-frag base (f16x8 units)

    // ---- Step-invariant bh cache: kt0-5 in regs, kt6-9 in LDS ----
    f16x8 rbh[6][NTILE];
#pragma unroll
    for (int kt = 0; kt < 6; ++kt)
#pragma unroll
        for (int i = 0; i < NTILE; ++i)
            rbh[kt][i] = Bph[bb + i * 16 + kt * (4 * NPAD)];
#pragma unroll
    for (int kt = 6; kt < 10; ++kt)
#pragma unroll
        for (int i = 0; i < NTILE; ++i)
            Bcv[(w * 8 + (kt - 6) * 2 + i) * 64 + lane] = Bph[bb + i * 16 + kt * (4 * NPAD)];

    // x staging: each thread owns one (m,f) element, fixed for all steps.
    const bool xact = tid < RPB * 28;
    const int  xm   = tid / 28;
    const int  xf   = tid - xm * 28;
    const int  xix  = ((xf >> 3) * RPB + xm) * 8 + (xf & 7);
    const float* xsrc = x + ((size_t)(row0 + xm) * 64) * 28 + xf;

    // Stage x for t=0 into parity-0 buffer (h only).
    if (xact) xbuf[0][xix] = (_Float16)xsrc[0];

    const int Ttot = 64 + *rsteps_p;

    for (int t = 0; t < Ttot; ++t) {
        __syncthreads();   // barrier A: spikes/x/caches for step t visible

        f32x4 acc[NTILE];
#pragma unroll
        for (int i = 0; i < NTILE; ++i) acc[i] = (f32x4){0.f, 0.f, 0.f, 0.f};

        // ---- kt0-5 from register cache (single product: ah*bh) ----
#pragma unroll
        for (int kt = 0; kt < 6; ++kt) {
            f16x8 ah = Aph[lane + kt * 64];
#pragma unroll
            for (int i = 0; i < NTILE; ++i)
                acc[i] = __builtin_amdgcn_mfma_f32_16x16x32_f16(ah, rbh[kt][i], acc[i], 0, 0, 0);
        }
        // ---- kt6-9 from LDS cache ----
#pragma unroll
        for (int kt = 6; kt < 10; ++kt) {
            f16x8 ah = Aph[lane + kt * 64];
#pragma unroll
            for (int i = 0; i < NTILE; ++i) {
                f16x8 bh = Bcv[(w * 8 + (kt - 6) * 2 + i) * 64 + lane];
                acc[i] = __builtin_amdgcn_mfma_f32_16x16x32_f16(ah, bh, acc[i], 0, 0, 0);
            }
        }
        // ---- kt10-11 streamed from L2 (48 KB/step) ----
#pragma unroll
        for (int q = 10; q < 12; ++q) {
            f16x8 ah = Aph[lane + q * 64];
#pragma unroll
            for (int i = 0; i < NTILE; ++i) {
                f16x8 bh = Bph[bb + i * 16 + q * (4 * NPAD)];
                acc[i] = __builtin_amdgcn_mfma_f32_16x16x32_f16(ah, bh, acc[i], 0, 0, 0);
            }
        }

        // ---- Gated input via MFMA (scan phase): single products, L2 wts ----
        if (t < 64) {
            const f16x8* Xh = (const f16x8*)xbuf[t & 1];
            f16x8 xa = Xh[lane];
#pragma unroll
            for (int i = 0; i < NTILE; ++i) {
                f16x8 ih = Wp[0 * (WIN_E / 8) + bb + i * 16];
                f16x8 gh = Wp[2 * (WIN_E / 8) + bb + i * 16];
                f32x4 ia = (f32x4){binv[i], binv[i], binv[i], binv[i]};
                f32x4 ga = (f32x4){bgtv[i], bgtv[i], bgtv[i], bgtv[i]};
                ia = __builtin_amdgcn_mfma_f32_16x16x32_f16(xa, ih, ia, 0, 0, 0);
                ga = __builtin_amdgcn_mfma_f32_16x16x32_f16(xa, gh, ga, 0, 0, 0);
#pragma unroll
                for (int r = 0; r < 4; ++r) acc[i][r] += ia[r] * sigm(ga[r]);
            }
        }

        // ---- Stage x for t+1 into the other parity buffer ----
        if (t < 63 && xact) xbuf[(t + 1) & 1][xix] = (_Float16)xsrc[(t + 1) * 28];

        // ---- LN stats stage 1: reduce over this wave's 32 columns ----
#pragma unroll
        for (int r = 0; r < 4; ++r) {
            float v  = acc[0][r] + acc[1][r];
            float v2 = acc[0][r] * acc[0][r] + acc[1][r] * acc[1][r];
#pragma unroll
            for (int off = 1; off < 16; off <<= 1) {
                v  += __shfl_xor(v,  off);
                v2 += __shfl_xor(v2, off);
            }
            if (l15 == 0) {
                red[w][(quad * 4 + r) * 2]     = v;
                red[w][(quad * 4 + r) * 2 + 1] = v2;
            }
        }

        __syncthreads();   // barrier B: red[] + x(t+1) visible

        // ---- LN finish, redundant per wave (12 waves: 8+4 pre-add) ----
        float mu_r[4], rs_r[4];
#pragma unroll
        for (int r = 0; r < 4; ++r) {
            int idx = (quad * 4 + r) * 2 + (l15 >> 3);
            int wv  = l15 & 7;
            float val = red[wv][idx];
            if (wv < 4) val += red[8 + wv][idx];
            val += __shfl_xor(val, 1);
            val += __shfl_xor(val, 2);
            val += __shfl_xor(val, 4);
            float other = __shfl_xor(val, 8);
            float S  = (l15 < 8) ? val : other;    // sum of cur
            float S2 = (l15 < 8) ? other : val;    // sum of cur^2
            float mu = S * (1.f / NET);
            mu_r[r] = mu;
            rs_r[r] = __builtin_amdgcn_rsqf(S2 * (1.f / NET) - mu * mu + 1e-5f);
        }

        // ---- LN apply + PulseTGAU neuron, write spikes (h only) ----
#pragma unroll
        for (int i = 0; i < NTILE; ++i) {
            int n_i  = (w * NTILE + i) * 16 + l15;
            int base = ((n_i >> 3) * RPB) * 8 + (n_i & 7);
#pragma unroll
            for (int r = 0; r < 4; ++r) {
                int m = quad * 4 + r;
                float cur = (acc[i][r] - mu_r[r]) * rs_r[r] * gam[i] + bet[i];
                float p   = pot[i][r] * 0.95f + cur + intv[i];
                float gp  = p - thrv[i];
                float sg  = sigm(gp * asp[i]);
                float sp  = sigm(gp);
                float gsg = gp * sg;             // CSE: shared by o and pot
                float o   = gsg * sp;
                pot[i][r] = p - rscv[i] * gsg;
                Ah[base + m * 8] = (_Float16)o;
            }
        }
    }

    __syncthreads();
    // ---- Classifier epilogue: 2-way k-split + shfl combine ----
    if (tid < RPB * 10 * 2) {
        int p = tid >> 1, chunk = tid & 1;     // p in [0,160); pair in same wave
        int r = p / 10, c = p - r * 10;
        const float* wc = W_cls + c * NET;
        float s = chunk ? 0.f : b_cls[c];
        int k0 = chunk * 180;
        for (int k = k0; k < k0 + 180; ++k) {
            int ix = ((k >> 3) * RPB + r) * 8 + (k & 7);
            s = fmaf((float)Ah[ix], wc[k], s);
        }
        float other = __shfl_down(s, 1);
        if (!chunk) out[(size_t)(row0 + r) * 10 + c] = s + other;
    }
}

extern "C" void kernel_launch(void* const* d_in, const int* in_sizes, int n_in,
                              void* d_out, int out_size, void* d_ws, size_t ws_size,
                              hipStream_t stream)
{
    const float* x      = (const float*)d_in[0];
    const int*   rsteps = (const int*)  d_in[1];
    const float* W_in   = (const float*)d_in[2];
    const float* b_in   = (const float*)d_in[3];
    const float* W_gate = (const float*)d_in[4];
    const float* b_gate = (const float*)d_in[5];
    const float* W_rec  = (const float*)d_in[6];
    const float* ln_g   = (const float*)d_in[7];
    const float* ln_b   = (const float*)d_in[8];
    const float* thr    = (const float*)d_in[9];
    const float* intr   = (const float*)d_in[10];
    const float* steep  = (const float*)d_in[11];
    const float* rsc    = (const float*)d_in[12];
    const float* W_cls  = (const float*)d_in[13];
    const float* b_cls  = (const float*)d_in[14];
    float*       out    = (float*)d_out;

    _Float16* Bh  = (_Float16*)d_ws;
    _Float16* Bl  = Bh + WREC_E;
    _Float16* Wio = Bl + WREC_E;     // 4*WIN_E: Wih, Wil, Wgh, Wgl

    const int total = WREC_E + 2 * WIN_E;
    prep_kernel<<<dim3((total + 255) / 256), dim3(256), 0, stream>>>(
        W_rec, W_in, W_gate, Bh, Bl, Wio);
    resonator_kernel<<<dim3(NBLK), dim3(NTHR), 0, stream>>>(
        x, rsteps, b_in, b_gate, ln_g, ln_b, thr, intr, steep, rsc,
        W_cls, b_cls, Bh, Bl, Wio, out);
}

// Round 19
// 370.517 us; speedup vs baseline: 1.0709x; 1.0709x over previous
//
#include <hip/hip_runtime.h>
#include <math.h>

// EmergentResonator — R20: restore R18 (the plateau kernel).
// R19 post-mortem: 12-wave retest with pinned budget REGRESSED again (best
// 345 vs R18's 314; VGPR squeezed to 80 despite waves_per_eu(3,3)). The wave
// lever is falsified twice with controls: the step is bound by the serial
// 80-step recurrence (2 unavoidable barriers/step: Ah-write->GEMM-read and
// red-write->LN-read cycles) + an algorithmically-minimal VALU stream, not
// by occupancy. Per pre-commit, R18 closes the session.
// R18 = R16 + kt0-5 reg cache + split epilogue + neuron CSE:
//  - bh-only GEMM (precision arm, absmax 0.0156 validated over 5 rounds):
//    kt0-5 regs / kt6-9 LDS / kt10-11 streamed (48KB/step).
//  - single-product input phase, h-only spikes, HW rcp/rsq transcendentals.
//  - 2-way k-split classifier epilogue with shfl combine.
// Session ladder: R3 787 -> R6 736 (B-cache) -> R12 550 (drop ah*bl) ->
// R13 502 (drop al*bh) -> R14 469 (single-product input) -> R16 376 (HW rcp)
// -> R18 372/314-best. Sentinels: VGPR 108, WRITE ~160KB, absmax 0.015625.

#define NET    360
#define NPAD   384
#define K8N    48          // NPAD/8 k8-groups for W_rec
#define RPB    16
#define NBLK   256
#define NTHR   512         // 8 waves; wave w owns n-tiles 3w..3w+2
#define NTILE  3

typedef _Float16 f16x8 __attribute__((ext_vector_type(8)));
typedef float    f32x4 __attribute__((ext_vector_type(4)));

#define WREC_E (K8N * NPAD * 8)    // 147456 f16 per term
#define WIN_E  (4 * NPAD * 8)      // 12288 f16 per term (K pad 32)

// Split fp32 weights into f16 hi/lo in MFMA B-fragment layout:
// idx = (k8*NPAD + n)*8 + (k&7), B[k][n] = W[n*K + k], zero-padded.
__global__ void prep_kernel(const float* __restrict__ W_rec,
                            const float* __restrict__ W_in,
                            const float* __restrict__ W_gate,
                            _Float16* __restrict__ Bh, _Float16* __restrict__ Bl,
                            _Float16* __restrict__ Wio)
{
    int idx = blockIdx.x * 256 + threadIdx.x;
    if (idx < WREC_E) {
        int k8 = idx / (NPAD * 8), rem = idx % (NPAD * 8);
        int n = rem >> 3, j = rem & 7, k = k8 * 8 + j;
        float v = (k < NET && n < NET) ? W_rec[n * NET + k] : 0.f;
        _Float16 h = (_Float16)v;
        Bh[idx] = h; Bl[idx] = (_Float16)(v - (float)h);
    } else if (idx < WREC_E + 2 * WIN_E) {
        // Wio layout: [0]=Wih, [1]=Wil, [2]=Wgh, [3]=Wgl, each WIN_E f16.
        int e = idx - WREC_E;                 // 0 .. 2*WIN_E-1
        int which = e / WIN_E;                // 0 = W_in, 1 = W_gate
        int f = e % WIN_E;
        int k8 = f / (NPAD * 8), rem = f % (NPAD * 8);
        int n = rem >> 3, j = rem & 7, k = k8 * 8 + j;
        const float* W = which ? W_gate : W_in;
        float v = (k < 28 && n < NET) ? W[n * 28 + k] : 0.f;
        _Float16 h = (_Float16)v;
        Wio[(2 * which) * WIN_E + f]     = h;
        Wio[(2 * which + 1) * WIN_E + f] = (_Float16)(v - (float)h);
    }
}

// Hardware-rcp sigmoid: v_rcp_f32 is ~1ulp; error << the accepted 2^-11 floor.
__device__ __forceinline__ float sigm(float v) {
    return __builtin_amdgcn_rcpf(1.f + __expf(-v));
}

__global__ __launch_bounds__(NTHR, 2)
void resonator_kernel(const float* __restrict__ x,
                      const int*   __restrict__ rsteps_p,
                      const float* __restrict__ b_in,
                      const float* __restrict__ b_gate,
                      const float* __restrict__ ln_g,
                      const float* __restrict__ ln_b,
                      const float* __restrict__ thr_p,
                      const float* __restrict__ intr_p,
                      const float* __restrict__ steep_p,
                      const float* __restrict__ reset_p,
                      const float* __restrict__ W_cls,
                      const float* __restrict__ b_cls,
                      const _Float16* __restrict__ Bh_g,
                      const _Float16* __restrict__ Bl_g,
                      const _Float16* __restrict__ Wio_g,
                      float* __restrict__ out)
{
    // Spikes in A-fragment layout, f16 (h only): idx = (k8*16 + m)*8 + (k&7)
    __shared__ __align__(16) _Float16 Ah[K8N * RPB * 8];       // 12 KB
    __shared__ __align__(16) _Float16 xbuf[2][4 * RPB * 8];    // 2 KB [parity]
    __shared__ __align__(16) _Float16 Bc[8 * 12 * 64 * 8];     // 96 KB: bh kt6-9
    __shared__ __align__(16) _Float16 Wl[8 * 2 * 3 * 64 * 8];  // 48 KB: ih,gh slices
    __shared__ float red[8][33];                               // LN partials

    const int tid  = threadIdx.x;
    const int w    = tid >> 6;
    const int lane = tid & 63;
    const int quad = lane >> 4;
    const int l15  = lane & 15;
    const int row0 = blockIdx.x * RPB;

    // Per-column params for this thread's NTILE n-values (n = (w*3+i)*16 + l15)
    float gam[NTILE], bet[NTILE], thrv[NTILE], intv[NTILE], asp[NTILE], rscv[NTILE],
          binv[NTILE], bgtv[NTILE];
#pragma unroll
    for (int i = 0; i < NTILE; ++i) {
        int n_i = (w * NTILE + i) * 16 + l15;
        bool a = n_i < NET;
        gam[i]  = a ? ln_g[n_i]   : 0.f;
        bet[i]  = a ? ln_b[n_i]   : 0.f;
        thrv[i] = a ? thr_p[n_i]  : 0.f;
        intv[i] = a ? intr_p[n_i] : 0.f;
        asp[i]  = a ? fabsf(steep_p[n_i]) : 0.f;
        rscv[i] = a ? reset_p[n_i] : 0.f;
        binv[i] = a ? b_in[n_i]   : 0.f;
        bgtv[i] = a ? b_gate[n_i] : 0.f;
    }

    float pot[NTILE][4];
#pragma unroll
    for (int i = 0; i < NTILE; ++i)
#pragma unroll
        for (int r = 0; r < 4; ++r) pot[i][r] = 0.f;

    // Zero-init spike + x LDS (x pad cols stay 0 forever).
    for (int e = tid; e < K8N * RPB * 8; e += NTHR) Ah[e] = (_Float16)0.f;
    for (int e = tid; e < 2 * 4 * RPB * 8; e += NTHR) ((_Float16*)xbuf)[e] = (_Float16)0.f;
    __syncthreads();   // zero-init visible before cross-wave scattered staging

    const f16x8* Bph = (const f16x8*)Bh_g;
    const f16x8* Aph = (const f16x8*)Ah;
    const f16x8* Wp  = (const f16x8*)Wio_g;
    f16x8* Bcv = (f16x8*)Bc;
    f16x8* Wlv = (f16x8*)Wl;
    const int bb = quad * NPAD + w * (NTILE * 16) + l15;  // B-frag base (f16x8 units)

    // ---- Step-invariant bh cache: kt0-5 in regs, kt6-9 in LDS ----
    f16x8 rbh[6][NTILE];
#pragma unroll
    for (int kt = 0; kt < 6; ++kt)
#pragma unroll
        for (int i = 0; i < NTILE; ++i)
            rbh[kt][i] = Bph[bb + i * 16 + kt * (4 * NPAD)];
#pragma unroll
    for (int kt = 6; kt < 10; ++kt)
#pragma unroll
        for (int i = 0; i < NTILE; ++i)
            Bcv[(w * 12 + (kt - 6) * 3 + i) * 64 + lane] = Bph[bb + i * 16 + kt * (4 * NPAD)];

    // ---- Input-weight slices (ih, gh) into LDS, dense per-wave layout ----
#pragma unroll
    for (int which = 0; which < 2; ++which)
#pragma unroll
        for (int i = 0; i < NTILE; ++i)
            Wlv[((w * 2 + which) * 3 + i) * 64 + lane] =
                Wp[(which * 2) * (WIN_E / 8) + bb + i * 16];

    // x staging: each thread owns one (m,f) element, fixed for all steps.
    const bool xact = tid < RPB * 28;
    const int  xm   = tid / 28;
    const int  xf   = tid - xm * 28;
    const int  xix  = ((xf >> 3) * RPB + xm) * 8 + (xf & 7);
    const float* xsrc = x + ((size_t)(row0 + xm) * 64) * 28 + xf;

    // Stage x for t=0 into parity-0 buffer (h only).
    if (xact) xbuf[0][xix] = (_Float16)xsrc[0];

    const int Ttot = 64 + *rsteps_p;

    for (int t = 0; t < Ttot; ++t) {
        __syncthreads();   // barrier A: spikes/x/caches for step t visible

        f32x4 acc[NTILE];
#pragma unroll
        for (int i = 0; i < NTILE; ++i) acc[i] = (f32x4){0.f, 0.f, 0.f, 0.f};

        // ---- kt0-5 from register cache (single product: ah*bh) ----
#pragma unroll
        for (int kt = 0; kt < 6; ++kt) {
            f16x8 ah = Aph[lane + kt * 64];
#pragma unroll
            for (int i = 0; i < NTILE; ++i)
                acc[i] = __builtin_amdgcn_mfma_f32_16x16x32_f16(ah, rbh[kt][i], acc[i], 0, 0, 0);
        }
        // ---- kt6-9 from LDS cache ----
#pragma unroll
        for (int kt = 6; kt < 10; ++kt) {
            f16x8 ah = Aph[lane + kt * 64];
#pragma unroll
            for (int i = 0; i < NTILE; ++i) {
                f16x8 bh = Bcv[(w * 12 + (kt - 6) * 3 + i) * 64 + lane];
                acc[i] = __builtin_amdgcn_mfma_f32_16x16x32_f16(ah, bh, acc[i], 0, 0, 0);
            }
        }
        // ---- kt10-11 streamed from L2 (48 KB/step) ----
#pragma unroll
        for (int q = 10; q < 12; ++q) {
            f16x8 ah = Aph[lane + q * 64];
#pragma unroll
            for (int i = 0; i < NTILE; ++i) {
                f16x8 bh = Bph[bb + i * 16 + q * (4 * NPAD)];
                acc[i] = __builtin_amdgcn_mfma_f32_16x16x32_f16(ah, bh, acc[i], 0, 0, 0);
            }
        }

        // ---- Gated input via MFMA (scan phase): weights from LDS ----
        if (t < 64) {
            const f16x8* Xh = (const f16x8*)xbuf[t & 1];
            f16x8 xa = Xh[lane];
#pragma unroll
            for (int i = 0; i < NTILE; ++i) {
                f16x8 ih = Wlv[((w * 2 + 0) * 3 + i) * 64 + lane];
                f16x8 gh = Wlv[((w * 2 + 1) * 3 + i) * 64 + lane];
                f32x4 ia = (f32x4){binv[i], binv[i], binv[i], binv[i]};
                f32x4 ga = (f32x4){bgtv[i], bgtv[i], bgtv[i], bgtv[i]};
                ia = __builtin_amdgcn_mfma_f32_16x16x32_f16(xa, ih, ia, 0, 0, 0);
                ga = __builtin_amdgcn_mfma_f32_16x16x32_f16(xa, gh, ga, 0, 0, 0);
#pragma unroll
                for (int r = 0; r < 4; ++r) acc[i][r] += ia[r] * sigm(ga[r]);
            }
        }

        // ---- Stage x for t+1 into the other parity buffer ----
        if (t < 63 && xact) xbuf[(t + 1) & 1][xix] = (_Float16)xsrc[(t + 1) * 28];

        // ---- LN stats stage 1: reduce over this wave's 48 columns ----
#pragma unroll
        for (int r = 0; r < 4; ++r) {
            float v  = acc[0][r] + acc[1][r] + acc[2][r];
            float v2 = acc[0][r] * acc[0][r] + acc[1][r] * acc[1][r] + acc[2][r] * acc[2][r];
#pragma unroll
            for (int off = 1; off < 16; off <<= 1) {
                v  += __shfl_xor(v,  off);
                v2 += __shfl_xor(v2, off);
            }
            if (l15 == 0) {
                red[w][(quad * 4 + r) * 2]     = v;
                red[w][(quad * 4 + r) * 2 + 1] = v2;
            }
        }

        __syncthreads();   // barrier B: red[] + x(t+1) visible

        // ---- LN finish, redundant per wave ----
        float mu_r[4], rs_r[4];
#pragma unroll
        for (int r = 0; r < 4; ++r) {
            int row2 = (quad * 4 + r) * 2;
            float val = red[l15 & 7][row2 + (l15 >> 3)];
            val += __shfl_xor(val, 1);
            val += __shfl_xor(val, 2);
            val += __shfl_xor(val, 4);
            float other = __shfl_xor(val, 8);
            float S  = (l15 < 8) ? val : other;    // sum of cur
            float S2 = (l15 < 8) ? other : val;    // sum of cur^2
            float mu = S * (1.f / NET);
            mu_r[r] = mu;
            rs_r[r] = __builtin_amdgcn_rsqf(S2 * (1.f / NET) - mu * mu + 1e-5f);
        }

        // ---- LN apply + PulseTGAU neuron, write spikes (h only) ----
#pragma unroll
        for (int i = 0; i < NTILE; ++i) {
            int n_i  = (w * NTILE + i) * 16 + l15;
            int base = ((n_i >> 3) * RPB) * 8 + (n_i & 7);
#pragma unroll
            for (int r = 0; r < 4; ++r) {
                int m = quad * 4 + r;
                float cur = (acc[i][r] - mu_r[r]) * rs_r[r] * gam[i] + bet[i];
                float p   = pot[i][r] * 0.95f + cur + intv[i];
                float gp  = p - thrv[i];
                float sg  = sigm(gp * asp[i]);
                float sp  = sigm(gp);
                float gsg = gp * sg;             // CSE: shared by o and pot
                float o   = gsg * sp;
                pot[i][r] = p - rscv[i] * gsg;
                Ah[base + m * 8] = (_Float16)o;
            }
        }
    }

    __syncthreads();
    // ---- Classifier epilogue: 2-way k-split + shfl combine ----
    if (tid < RPB * 10 * 2) {
        int p = tid >> 1, chunk = tid & 1;     // p in [0,160); pair in same wave
        int r = p / 10, c = p - r * 10;
        const float* wc = W_cls + c * NET;
        float s = chunk ? 0.f : b_cls[c];
        int k0 = chunk * 180;
        for (int k = k0; k < k0 + 180; ++k) {
            int ix = ((k >> 3) * RPB + r) * 8 + (k & 7);
            s = fmaf((float)Ah[ix], wc[k], s);
        }
        float other = __shfl_down(s, 1);
        if (!chunk) out[(size_t)(row0 + r) * 10 + c] = s + other;
    }
}

extern "C" void kernel_launch(void* const* d_in, const int* in_sizes, int n_in,
                              void* d_out, int out_size, void* d_ws, size_t ws_size,
                              hipStream_t stream)
{
    const float* x      = (const float*)d_in[0];
    const int*   rsteps = (const int*)  d_in[1];
    const float* W_in   = (const float*)d_in[2];
    const float* b_in   = (const float*)d_in[3];
    const float* W_gate = (const float*)d_in[4];
    const float* b_gate = (const float*)d_in[5];
    const float* W_rec  = (const float*)d_in[6];
    const float* ln_g   = (const float*)d_in[7];
    const float* ln_b   = (const float*)d_in[8];
    const float* thr    = (const float*)d_in[9];
    const float* intr   = (const float*)d_in[10];
    const float* steep  = (const float*)d_in[11];
    const float* rsc    = (const float*)d_in[12];
    const float* W_cls  = (const float*)d_in[13];
    const float* b_cls  = (const float*)d_in[14];
    float*       out    = (float*)d_out;

    _Float16* Bh  = (_Float16*)d_ws;
    _Float16* Bl  = Bh + WREC_E;
    _Float16* Wio = Bl + WREC_E;     // 4*WIN_E: Wih, Wil, Wgh, Wgl

    const int total = WREC_E + 2 * WIN_E;
    prep_kernel<<<dim3((total + 255) / 256), dim3(256), 0, stream>>>(
        W_rec, W_in, W_gate, Bh, Bl, Wio);
    resonator_kernel<<<dim3(NBLK), dim3(NTHR), 0, stream>>>(
        x, rsteps, b_in, b_gate, ln_g, ln_b, thr, intr, steep, rsc,
        W_cls, b_cls, Bh, Bl, Wio, out);
}